// Round 9
// baseline (170.471 us; speedup 1.0000x reference)
//
#include <hip/hip_runtime.h>

// HybridSymmetricLoss: B=65536, T=3, J=10 (fp32).
// C[tl][ta] = sum_jk BCE(assign[b,ta,jk], labels[b,tl,jk]);
// loss = min over 6 perms of mean C[t][perm[t]] + category BCE under the
// argmin perm.  Logs in log2 space (clip -100/ln2), one ln2 scale at end.
//
// R9 = R7 carrier (one b per 32-lane half-wave; best measured) with SPLIT
// load policy: assignments via NORMAL loads (served from the dirty L2/L3
// lines the harness restore just wrote), labels via NON-TEMPORAL loads
// (HBM path).  Theory: the two 78.6 MB streams ride different service
// paths concurrently instead of sharing one (R5 normal-only: 2.5 TB/s;
// R7 NT-only: ~3.7 TB/s).  Two-pass final sum via d_ws.

#define CLIP2 (-144.26950408889634f)   // -100 / ln(2)
#define LN2   (0.6931471805599453f)

typedef float vfloat4 __attribute__((ext_vector_type(4)));

__launch_bounds__(256)
__global__ void hybrid_pass1(const float* __restrict__ assign,
                             const float* __restrict__ cat,
                             const float* __restrict__ assign_lab,
                             const float* __restrict__ cat_lab,
                             float* __restrict__ ws, int B) {
    const int sub = threadIdx.x & 31;               // lane within half-wave
    const int b   = (blockIdx.x * blockDim.x + threadIdx.x) >> 5;
    if (b >= B) return;

    const bool act = sub < 25;                      // 25 lanes * 4 = 100 jk
    float e[3][3] = {{0.f,0.f,0.f},{0.f,0.f,0.f},{0.f,0.f,0.f}};

    if (act) {
        const vfloat4* Ab = (const vfloat4*)(assign     + (size_t)b * 300 + sub * 4);
        const vfloat4* Yb = (const vfloat4*)(assign_lab + (size_t)b * 300 + sub * 4);
        vfloat4 av[3], yv[3];
        #pragma unroll
        for (int t = 0; t < 3; ++t) {
            av[t] = Ab[t * 25];                                // normal (cache path)
            yv[t] = __builtin_nontemporal_load(Yb + t * 25);   // NT (HBM path)
        }

        float d[3][4];
        float s1p[3] = {0.f, 0.f, 0.f};
        #pragma unroll
        for (int t = 0; t < 3; ++t) {
            #pragma unroll
            for (int c = 0; c < 4; ++c) {
                float a  = av[t][c];
                float lp = fmaxf(__log2f(a),        CLIP2);
                float l1 = fmaxf(__log2f(1.0f - a), CLIP2);
                d[t][c] = lp - l1;
                s1p[t] += l1;
            }
        }
        #pragma unroll
        for (int tl = 0; tl < 3; ++tl) {
            #pragma unroll
            for (int ta = 0; ta < 3; ++ta) {
                float acc = s1p[ta];
                #pragma unroll
                for (int c = 0; c < 4; ++c)
                    acc = fmaf(yv[tl][c], d[ta][c], acc);
                e[tl][ta] = acc;
            }
        }
    }

    // category prefetch so its latency overlaps the butterfly
    float cb0=0.f,cb1=0.f,cb2=0.f,gb0=0.f,gb1=0.f,gb2=0.f;
    if (sub == 0) {
        const float* cp = cat     + (size_t)b * 3;
        const float* gp = cat_lab + (size_t)b * 3;
        cb0 = cp[0]; cb1 = cp[1]; cb2 = cp[2];
        gb0 = gp[0]; gb1 = gp[1]; gb2 = gp[2];
    }

    // 5-stage butterfly within each 32-lane half (both halves in parallel)
    #pragma unroll
    for (int off = 1; off <= 16; off <<= 1)
        #pragma unroll
        for (int tl = 0; tl < 3; ++tl)
            #pragma unroll
            for (int ta = 0; ta < 3; ++ta)
                e[tl][ta] += __shfl_xor(e[tl][ta], off, 64);

    float lsum = 0.f;
    if (sub == 0) {
        // min over perms of C = -ln2*e  ==  max over perms of e
        const int P0[6] = {0,0,1,1,2,2};
        const int P1[6] = {1,2,0,2,0,1};
        const int P2[6] = {2,1,2,0,1,0};
        float best = e[0][0] + e[1][1] + e[2][2];
        int bp0 = 0, bp1 = 1, bp2 = 2;
        #pragma unroll
        for (int p = 1; p < 6; ++p) {
            float l = e[0][P0[p]] + e[1][P1[p]] + e[2][P2[p]];
            if (l > best) { best = l; bp0 = P0[p]; bp1 = P1[p]; bp2 = P2[p]; }
        }

        float lp0 = fmaxf(__log2f(cb0), CLIP2), l10 = fmaxf(__log2f(1.f-cb0), CLIP2);
        float lp1 = fmaxf(__log2f(cb1), CLIP2), l11 = fmaxf(__log2f(1.f-cb1), CLIP2);
        float lp2 = fmaxf(__log2f(cb2), CLIP2), l12 = fmaxf(__log2f(1.f-cb2), CLIP2);

        float lpa = (bp0==0)?lp0:((bp0==1)?lp1:lp2);
        float l1a = (bp0==0)?l10:((bp0==1)?l11:l12);
        float lpb = (bp1==0)?lp0:((bp1==1)?lp1:lp2);
        float l1b = (bp1==0)?l10:((bp1==1)?l11:l12);
        float lpc = (bp2==0)?lp0:((bp2==1)?lp1:lp2);
        float l1c = (bp2==0)?l10:((bp2==1)?l11:l12);

        float csum = -(gb0*lpa + (1.f-gb0)*l1a
                     + gb1*lpb + (1.f-gb1)*l1b
                     + gb2*lpc + (1.f-gb2)*l1c);

        lsum = best * (-1.f/300.f) + csum * (1.f/3.f);
    }

    // block reduce: 8 half-wave leaders per 256-thread block
    __shared__ float sred[8];
    if (sub == 0) sred[threadIdx.x >> 5] = lsum;
    __syncthreads();
    if (threadIdx.x == 0) {
        float s = 0.f;
        #pragma unroll
        for (int i = 0; i < 8; ++i) s += sred[i];
        ws[blockIdx.x] = s * (LN2 / (float)B);
    }
}

__launch_bounds__(1024)
__global__ void hybrid_pass2(const float* __restrict__ ws,
                             float* __restrict__ out, int n) {
    float s = 0.f;
    for (int i = threadIdx.x; i < n; i += 1024) s += ws[i];
    #pragma unroll
    for (int off = 32; off > 0; off >>= 1) s += __shfl_xor(s, off, 64);
    __shared__ float sm[16];
    if ((threadIdx.x & 63) == 0) sm[threadIdx.x >> 6] = s;
    __syncthreads();
    if (threadIdx.x == 0) {
        float t = 0.f;
        #pragma unroll
        for (int i = 0; i < 16; ++i) t += sm[i];
        out[0] = t;
    }
}

extern "C" void kernel_launch(void* const* d_in, const int* in_sizes, int n_in,
                              void* d_out, int out_size, void* d_ws, size_t ws_size,
                              hipStream_t stream) {
    const float* assign     = (const float*)d_in[0];
    const float* cat        = (const float*)d_in[1];
    const float* assign_lab = (const float*)d_in[2];
    const float* cat_lab    = (const float*)d_in[3];
    float* out = (float*)d_out;
    float* ws  = (float*)d_ws;

    const int B = in_sizes[0] / 300;               // T*J*J = 300
    const int blocks = (B * 32 + 255) / 256;       // one b per 32-lane half

    hybrid_pass1<<<blocks, 256, 0, stream>>>(assign, cat, assign_lab,
                                             cat_lab, ws, B);
    hybrid_pass2<<<1, 1024, 0, stream>>>(ws, out, blocks);
}

// Round 10
// 165.733 us; speedup vs baseline: 1.0286x; 1.0286x over previous
//
#include <hip/hip_runtime.h>

// HybridSymmetricLoss: B=65536, T=3, J=10 (fp32).
// C[tl][ta] = sum_jk BCE(assign[b,ta,jk], labels[b,tl,jk]);
// loss = min over 6 perms of mean C[t][perm[t]] + category BCE under the
// argmin perm.  Logs in log2 space (clip -100/ln2), one ln2 scale at end.
//
// R10 = exact revert to R7 (best measured: 164.5 us total).
// Carrier: one b per 32-lane half-wave, lanes 0..24 hold 4 jk via float4,
// 5-stage intra-half butterfly of 9 folded partials, NON-TEMPORAL loads on
// both 78.6 MB arrays (NT-everything is the fastest policy: R5 normal-only
// 2.5 TB/s, R7 NT-only 3.7 TB/s, R9 split regressed).
// Two-pass final sum via d_ws.

#define CLIP2 (-144.26950408889634f)   // -100 / ln(2)
#define LN2   (0.6931471805599453f)

typedef float vfloat4 __attribute__((ext_vector_type(4)));

__launch_bounds__(256)
__global__ void hybrid_pass1(const float* __restrict__ assign,
                             const float* __restrict__ cat,
                             const float* __restrict__ assign_lab,
                             const float* __restrict__ cat_lab,
                             float* __restrict__ ws, int B) {
    const int sub = threadIdx.x & 31;               // lane within half-wave
    const int b   = (blockIdx.x * blockDim.x + threadIdx.x) >> 5;
    if (b >= B) return;

    const bool act = sub < 25;                      // 25 lanes * 4 = 100 jk
    float e[3][3] = {{0.f,0.f,0.f},{0.f,0.f,0.f},{0.f,0.f,0.f}};

    if (act) {
        const vfloat4* Ab = (const vfloat4*)(assign     + (size_t)b * 300 + sub * 4);
        const vfloat4* Yb = (const vfloat4*)(assign_lab + (size_t)b * 300 + sub * 4);
        vfloat4 av[3], yv[3];
        #pragma unroll
        for (int t = 0; t < 3; ++t) {
            av[t] = __builtin_nontemporal_load(Ab + t * 25);   // +100 floats
            yv[t] = __builtin_nontemporal_load(Yb + t * 25);
        }

        float d[3][4];
        float s1p[3] = {0.f, 0.f, 0.f};
        #pragma unroll
        for (int t = 0; t < 3; ++t) {
            #pragma unroll
            for (int c = 0; c < 4; ++c) {
                float a  = av[t][c];
                float lp = fmaxf(__log2f(a),        CLIP2);
                float l1 = fmaxf(__log2f(1.0f - a), CLIP2);
                d[t][c] = lp - l1;
                s1p[t] += l1;
            }
        }
        #pragma unroll
        for (int tl = 0; tl < 3; ++tl) {
            #pragma unroll
            for (int ta = 0; ta < 3; ++ta) {
                float acc = s1p[ta];
                #pragma unroll
                for (int c = 0; c < 4; ++c)
                    acc = fmaf(yv[tl][c], d[ta][c], acc);
                e[tl][ta] = acc;
            }
        }
    }

    // category prefetch so its latency overlaps the butterfly
    float cb0=0.f,cb1=0.f,cb2=0.f,gb0=0.f,gb1=0.f,gb2=0.f;
    if (sub == 0) {
        const float* cp = cat     + (size_t)b * 3;
        const float* gp = cat_lab + (size_t)b * 3;
        cb0 = cp[0]; cb1 = cp[1]; cb2 = cp[2];
        gb0 = gp[0]; gb1 = gp[1]; gb2 = gp[2];
    }

    // 5-stage butterfly within each 32-lane half (both halves in parallel)
    #pragma unroll
    for (int off = 1; off <= 16; off <<= 1)
        #pragma unroll
        for (int tl = 0; tl < 3; ++tl)
            #pragma unroll
            for (int ta = 0; ta < 3; ++ta)
                e[tl][ta] += __shfl_xor(e[tl][ta], off, 64);

    float lsum = 0.f;
    if (sub == 0) {
        // min over perms of C = -ln2*e  ==  max over perms of e
        const int P0[6] = {0,0,1,1,2,2};
        const int P1[6] = {1,2,0,2,0,1};
        const int P2[6] = {2,1,2,0,1,0};
        float best = e[0][0] + e[1][1] + e[2][2];
        int bp0 = 0, bp1 = 1, bp2 = 2;
        #pragma unroll
        for (int p = 1; p < 6; ++p) {
            float l = e[0][P0[p]] + e[1][P1[p]] + e[2][P2[p]];
            if (l > best) { best = l; bp0 = P0[p]; bp1 = P1[p]; bp2 = P2[p]; }
        }

        float lp0 = fmaxf(__log2f(cb0), CLIP2), l10 = fmaxf(__log2f(1.f-cb0), CLIP2);
        float lp1 = fmaxf(__log2f(cb1), CLIP2), l11 = fmaxf(__log2f(1.f-cb1), CLIP2);
        float lp2 = fmaxf(__log2f(cb2), CLIP2), l12 = fmaxf(__log2f(1.f-cb2), CLIP2);

        float lpa = (bp0==0)?lp0:((bp0==1)?lp1:lp2);
        float l1a = (bp0==0)?l10:((bp0==1)?l11:l12);
        float lpb = (bp1==0)?lp0:((bp1==1)?lp1:lp2);
        float l1b = (bp1==0)?l10:((bp1==1)?l11:l12);
        float lpc = (bp2==0)?lp0:((bp2==1)?lp1:lp2);
        float l1c = (bp2==0)?l10:((bp2==1)?l11:l12);

        float csum = -(gb0*lpa + (1.f-gb0)*l1a
                     + gb1*lpb + (1.f-gb1)*l1b
                     + gb2*lpc + (1.f-gb2)*l1c);

        lsum = best * (-1.f/300.f) + csum * (1.f/3.f);
    }

    // block reduce: 8 half-wave leaders per 256-thread block
    __shared__ float sred[8];
    if (sub == 0) sred[threadIdx.x >> 5] = lsum;
    __syncthreads();
    if (threadIdx.x == 0) {
        float s = 0.f;
        #pragma unroll
        for (int i = 0; i < 8; ++i) s += sred[i];
        ws[blockIdx.x] = s * (LN2 / (float)B);
    }
}

__launch_bounds__(1024)
__global__ void hybrid_pass2(const float* __restrict__ ws,
                             float* __restrict__ out, int n) {
    float s = 0.f;
    for (int i = threadIdx.x; i < n; i += 1024) s += ws[i];
    #pragma unroll
    for (int off = 32; off > 0; off >>= 1) s += __shfl_xor(s, off, 64);
    __shared__ float sm[16];
    if ((threadIdx.x & 63) == 0) sm[threadIdx.x >> 6] = s;
    __syncthreads();
    if (threadIdx.x == 0) {
        float t = 0.f;
        #pragma unroll
        for (int i = 0; i < 16; ++i) t += sm[i];
        out[0] = t;
    }
}

extern "C" void kernel_launch(void* const* d_in, const int* in_sizes, int n_in,
                              void* d_out, int out_size, void* d_ws, size_t ws_size,
                              hipStream_t stream) {
    const float* assign     = (const float*)d_in[0];
    const float* cat        = (const float*)d_in[1];
    const float* assign_lab = (const float*)d_in[2];
    const float* cat_lab    = (const float*)d_in[3];
    float* out = (float*)d_out;
    float* ws  = (float*)d_ws;

    const int B = in_sizes[0] / 300;               // T*J*J = 300
    const int blocks = (B * 32 + 255) / 256;       // one b per 32-lane half

    hybrid_pass1<<<blocks, 256, 0, stream>>>(assign, cat, assign_lab,
                                             cat_lab, ws, B);
    hybrid_pass2<<<1, 1024, 0, stream>>>(ws, out, blocks);
}